// Round 1
// baseline (1048.061 us; speedup 1.0000x reference)
//
#include <hip/hip_runtime.h>
#include <math.h>

#define NCLU 196
#define DIM  256
#define TEMPERATURE 0.5f
#define EPSV 1e-12f

// K1 geometry
#define SLICES 8        // dim slices of 32
#define DPS    32       // dims per slice
#define F4PS   8        // float4s per slice
#define CHUNKS 96       // sample chunks -> 768 blocks = 3/CU (LDS-limited)
#define TPB    256
#define SPI    32       // samples per iteration per block = TPB/F4PS

// ---- block reduction helpers (256 threads = 4 waves of 64) ----
__device__ inline float blockReduceSum(float v, volatile float* sbuf) {
#pragma unroll
  for (int off = 32; off >= 1; off >>= 1) v += __shfl_xor(v, off, 64);
  const int lane = threadIdx.x & 63;
  const int wv   = threadIdx.x >> 6;
  __syncthreads();                 // protect sbuf against previous use
  if (lane == 0) sbuf[wv] = v;
  __syncthreads();
  return sbuf[0] + sbuf[1] + sbuf[2] + sbuf[3];
}

__device__ inline float blockReduceMax(float v, volatile float* sbuf) {
#pragma unroll
  for (int off = 32; off >= 1; off >>= 1) v = fmaxf(v, __shfl_xor(v, off, 64));
  const int lane = threadIdx.x & 63;
  const int wv   = threadIdx.x >> 6;
  __syncthreads();
  if (lane == 0) sbuf[wv] = v;
  __syncthreads();
  return fmaxf(fmaxf(sbuf[0], sbuf[1]), fmaxf(sbuf[2], sbuf[3]));
}

// ---- K1: segment sums of q and k + counts, LDS-accumulated ----
__global__ __launch_bounds__(TPB) void k_segsum(
    const float* __restrict__ q, const float* __restrict__ k,
    const int* __restrict__ lab, int n,
    float* __restrict__ gsq, float* __restrict__ gsk, float* __restrict__ gcnt) {
  __shared__ float lq[NCLU * DPS];   // 25088 B
  __shared__ float lk[NCLU * DPS];   // 25088 B
  __shared__ float lc[NCLU];
  const int tid   = threadIdx.x;
  const int slice = blockIdx.x;      // 0..SLICES-1
  const int chunk = blockIdx.y;      // 0..CHUNKS-1

  for (int i = tid; i < NCLU * DPS; i += TPB) { lq[i] = 0.f; lk[i] = 0.f; }
  if (tid < NCLU) lc[tid] = 0.f;
  __syncthreads();

  const int sub = tid >> 3;          // 0..31 : sample sub-index
  const int f4  = tid & 7;           // 0..7  : float4 within slice
  const float4* __restrict__ q4 = (const float4*)q;
  const float4* __restrict__ k4 = (const float4*)k;
  const int d4 = slice * F4PS + f4;
  const int stride = CHUNKS * SPI;   // 3072 samples / grid iteration

  for (int s = chunk * SPI + sub; s < n; s += stride) {
    const int L = lab[s];
    const float4 vq = q4[(long)s * (DIM / 4) + d4];
    const float4 vk = k4[(long)s * (DIM / 4) + d4];
    const int base = L * DPS + f4 * 4;
    atomicAdd(&lq[base + 0], vq.x);
    atomicAdd(&lq[base + 1], vq.y);
    atomicAdd(&lq[base + 2], vq.z);
    atomicAdd(&lq[base + 3], vq.w);
    atomicAdd(&lk[base + 0], vk.x);
    atomicAdd(&lk[base + 1], vk.y);
    atomicAdd(&lk[base + 2], vk.z);
    atomicAdd(&lk[base + 3], vk.w);
    if (slice == 0 && f4 == 0) atomicAdd(&lc[L], 1.0f);
  }
  __syncthreads();

  for (int i = tid; i < NCLU * DPS; i += TPB) {
    const int row = i >> 5, col = i & 31;
    atomicAdd(&gsq[row * DIM + slice * DPS + col], lq[i]);
    atomicAdd(&gsk[row * DIM + slice * DPS + col], lk[i]);
  }
  if (slice == 0)
    for (int i = tid; i < NCLU; i += TPB) atomicAdd(&gcnt[i], lc[i]);
}

// ---- K2: centers = normalize(sums/counts); also transposed copy + d_k ----
__global__ __launch_bounds__(TPB) void k_centers(
    const float* __restrict__ gsq, const float* __restrict__ gsk,
    const float* __restrict__ gcnt,
    float* __restrict__ qc, float* __restrict__ kc,
    float* __restrict__ qcT, float* __restrict__ dk) {
  __shared__ float sbuf[4];
  const int c = blockIdx.x, t = threadIdx.x;   // t indexes dim (DIM == TPB)
  const float denom = fmaxf(gcnt[c], EPSV);
  const float sq = gsq[c * DIM + t] / denom;
  const float sk = gsk[c * DIM + t] / denom;
  const float nq = blockReduceSum(sq * sq, sbuf);
  const float nk = blockReduceSum(sk * sk, sbuf);
  const float qv = sq / fmaxf(sqrtf(nq), EPSV);
  const float kv = sk / fmaxf(sqrtf(nk), EPSV);
  qc[c * DIM + t] = qv;
  kc[c * DIM + t] = kv;
  qcT[t * NCLU + c] = qv;
  const float dot = blockReduceSum(qv * kv, sbuf);
  if (t == 0) dk[c] = dot / TEMPERATURE;
}

// ---- K3: per-row similarity + masked logsumexp -> row loss ----
__global__ __launch_bounds__(TPB) void k_rowloss(
    const float* __restrict__ qc, const float* __restrict__ qcT,
    const float* __restrict__ dk, const float* __restrict__ gcnt,
    float* __restrict__ rowloss) {
  __shared__ float qrow[DIM];
  __shared__ float sbuf[4];
  const int c = blockIdx.x, t = threadIdx.x;
  qrow[t] = qc[c * DIM + t];
  __syncthreads();

  float v = -INFINITY;
  if (t < NCLU) {
    float dot = 0.f;
#pragma unroll 8
    for (int d = 0; d < DIM; ++d) dot += qrow[d] * qcT[d * NCLU + t];
    v = dot * (1.0f / TEMPERATURE);       // /0.5 == *2.0, exact
    if (t == c) v = dk[c];                // diag <- d_k (already /T)
    if (gcnt[t] == 0.f) v = -10.f;        // column mask AFTER diag set
  }
  const float m    = blockReduceMax(v, sbuf);
  const float e    = (t < NCLU) ? expf(v - m) : 0.f;
  const float ssum = blockReduceSum(e, sbuf);
  if (t == 0) {
    float loss = 0.f;
    if (gcnt[c] != 0.f) loss = -dk[c] + m + logf(ssum);
    rowloss[c] = loss;
  }
}

// ---- K4: final scalar ----
__global__ __launch_bounds__(TPB) void k_final(
    const float* __restrict__ rowloss, const float* __restrict__ gcnt,
    float* __restrict__ out) {
  __shared__ float sbuf[4];
  const int t = threadIdx.x;
  const float ls = (t < NCLU) ? rowloss[t] : 0.f;
  const float nz = (t < NCLU && gcnt[t] == 0.f) ? 1.f : 0.f;
  const float total = blockReduceSum(ls, sbuf);
  const float nzero = blockReduceSum(nz, sbuf);
  if (t == 0) out[0] = total / ((float)NCLU - nzero);
}

extern "C" void kernel_launch(void* const* d_in, const int* in_sizes, int n_in,
                              void* d_out, int out_size, void* d_ws, size_t ws_size,
                              hipStream_t stream) {
  const float* q  = (const float*)d_in[0];
  const float* k  = (const float*)d_in[1];
  const int* lab  = (const int*)d_in[2];
  const int n = in_sizes[0] / DIM;

  float* ws      = (float*)d_ws;
  float* gsq     = ws;                    // NCLU*DIM
  float* gsk     = gsq + NCLU * DIM;      // NCLU*DIM
  float* gcnt    = gsk + NCLU * DIM;      // NCLU   (end of zeroed region)
  float* qc      = gcnt + NCLU;           // NCLU*DIM
  float* kc      = qc + NCLU * DIM;       // NCLU*DIM
  float* qcT     = kc + NCLU * DIM;       // DIM*NCLU
  float* dk      = qcT + DIM * NCLU;      // NCLU
  float* rowloss = dk + NCLU;             // NCLU

  // d_ws is re-poisoned to 0xAA before every launch: zero the accumulators.
  hipMemsetAsync(d_ws, 0, (size_t)(2 * NCLU * DIM + NCLU) * sizeof(float), stream);

  dim3 g1(SLICES, CHUNKS);
  k_segsum <<<g1,   TPB, 0, stream>>>(q, k, lab, n, gsq, gsk, gcnt);
  k_centers<<<NCLU, TPB, 0, stream>>>(gsq, gsk, gcnt, qc, kc, qcT, dk);
  k_rowloss<<<NCLU, TPB, 0, stream>>>(qc, qcT, dk, gcnt, rowloss);
  k_final  <<<1,    TPB, 0, stream>>>(rowloss, gcnt, (float*)d_out);
}

// Round 3
// 564.392 us; speedup vs baseline: 1.8570x; 1.8570x over previous
//
#include <hip/hip_runtime.h>
#include <math.h>

#define NCLU 196
#define DIM  256
#define DV4  (DIM / 4)
#define TEMPERATURE 0.5f
#define EPSV 1e-12f
#define TPB  256
#define SPLIT 8      // gather blocks per cluster
#define CAP  256     // staged indices per tile
#define HBLK 256     // histogram blocks
#define SBLK 256     // scatter blocks

// ---- block reduction helpers (256 threads = 4 waves of 64) ----
__device__ inline float blockReduceSum(float v, volatile float* sbuf) {
#pragma unroll
  for (int off = 32; off >= 1; off >>= 1) v += __shfl_xor(v, off, 64);
  const int lane = threadIdx.x & 63;
  const int wv   = threadIdx.x >> 6;
  __syncthreads();
  if (lane == 0) sbuf[wv] = v;
  __syncthreads();
  return sbuf[0] + sbuf[1] + sbuf[2] + sbuf[3];
}

__device__ inline float blockReduceMax(float v, volatile float* sbuf) {
#pragma unroll
  for (int off = 32; off >= 1; off >>= 1) v = fmaxf(v, __shfl_xor(v, off, 64));
  const int lane = threadIdx.x & 63;
  const int wv   = threadIdx.x >> 6;
  __syncthreads();
  if (lane == 0) sbuf[wv] = v;
  __syncthreads();
  return fmaxf(fmaxf(sbuf[0], sbuf[1]), fmaxf(sbuf[2], sbuf[3]));
}

// ---- K0: global histogram of labels ----
__global__ __launch_bounds__(TPB) void k_hist(const int* __restrict__ lab, int n,
                                              int* __restrict__ ghist) {
  __shared__ int lh[NCLU];
  for (int i = threadIdx.x; i < NCLU; i += TPB) lh[i] = 0;
  __syncthreads();
  const int4* l4 = (const int4*)lab;
  const int n4 = n >> 2;
  for (int i = blockIdx.x * TPB + threadIdx.x; i < n4; i += gridDim.x * TPB) {
    const int4 v = l4[i];
    atomicAdd(&lh[v.x], 1); atomicAdd(&lh[v.y], 1);
    atomicAdd(&lh[v.z], 1); atomicAdd(&lh[v.w], 1);
  }
  __syncthreads();
  for (int i = threadIdx.x; i < NCLU; i += TPB)
    if (lh[i]) atomicAdd(&ghist[i], lh[i]);
}

// ---- K0b: exclusive scan -> offsets, init cursors ----
__global__ void k_scan(const int* __restrict__ ghist, int* __restrict__ offsets,
                       int* __restrict__ gcursor) {
  if (threadIdx.x == 0) {
    int acc = 0;
    for (int c = 0; c < NCLU; ++c) {
      offsets[c] = acc; gcursor[c] = acc; acc += ghist[c];
    }
  }
}

// ---- K1: counting-sort sample indices by label (two-pass LDS ticketing) ----
__global__ __launch_bounds__(TPB) void k_scatter(const int* __restrict__ lab, int n,
                                                 int* __restrict__ gcursor,
                                                 int* __restrict__ order) {
  __shared__ int lh[NCLU];
  __shared__ int lbase[NCLU];
  const int chunk = (n + gridDim.x - 1) / gridDim.x;
  const int start = blockIdx.x * chunk;
  const int end = min(n, start + chunk);
  for (int i = threadIdx.x; i < NCLU; i += TPB) lh[i] = 0;
  __syncthreads();
  for (int s = start + threadIdx.x; s < end; s += TPB) atomicAdd(&lh[lab[s]], 1);
  __syncthreads();
  for (int i = threadIdx.x; i < NCLU; i += TPB) {
    const int c = lh[i];
    lbase[i] = c ? atomicAdd(&gcursor[i], c) : 0;
  }
  __syncthreads();
  for (int i = threadIdx.x; i < NCLU; i += TPB) lh[i] = 0;   // reuse as local cursor
  __syncthreads();
  for (int s = start + threadIdx.x; s < end; s += TPB) {
    const int c = lab[s];
    const int p = atomicAdd(&lh[c], 1);
    order[lbase[c] + p] = s;
  }
}

// ---- K2: gather-reduce; register accumulators, zero atomics in hot loop ----
__global__ __launch_bounds__(TPB) void k_gather(
    const float* __restrict__ q, const float* __restrict__ k,
    const int* __restrict__ order, const int* __restrict__ offsets,
    const int* __restrict__ ghist,
    float* __restrict__ gsq, float* __restrict__ gsk) {
  const int c = blockIdx.x, p = blockIdx.y;
  const int base = offsets[c];
  const int len = ghist[c];
  const int lo = (int)(((long)len * p) / SPLIT);
  const int hi = (int)(((long)len * (p + 1)) / SPLIT);
  const int cnt = hi - lo;
  if (cnt <= 0) return;                       // uniform across block
  __shared__ int sidx[CAP];
  const int lane = threadIdx.x & 63;
  const int w = threadIdx.x >> 6;
  const float4* __restrict__ q4 = (const float4*)q;
  const float4* __restrict__ k4 = (const float4*)k;
  float aqx = 0.f, aqy = 0.f, aqz = 0.f, aqw = 0.f;
  float akx = 0.f, aky = 0.f, akz = 0.f, akw = 0.f;

  for (int tile = 0; tile < cnt; tile += CAP) {
    const int tc = min(CAP, cnt - tile);
    __syncthreads();
    for (int i = threadIdx.x; i < tc; i += TPB) sidx[i] = order[base + lo + tile + i];
    __syncthreads();
#pragma unroll 4
    for (int i = w; i < tc; i += 4) {
      const int idx = sidx[i];
      const float4 vq = q4[(long)idx * DV4 + lane];
      const float4 vk = k4[(long)idx * DV4 + lane];
      aqx += vq.x; aqy += vq.y; aqz += vq.z; aqw += vq.w;
      akx += vk.x; aky += vk.y; akz += vk.z; akw += vk.w;
    }
  }
  const int o = c * DIM + lane * 4;
  atomicAdd(&gsq[o + 0], aqx); atomicAdd(&gsq[o + 1], aqy);
  atomicAdd(&gsq[o + 2], aqz); atomicAdd(&gsq[o + 3], aqw);
  atomicAdd(&gsk[o + 0], akx); atomicAdd(&gsk[o + 1], aky);
  atomicAdd(&gsk[o + 2], akz); atomicAdd(&gsk[o + 3], akw);
}

// ---- K3: centers = normalize(sums/counts); transposed copy + d_k ----
__global__ __launch_bounds__(TPB) void k_centers(
    const float* __restrict__ gsq, const float* __restrict__ gsk,
    const int* __restrict__ gcnt,
    float* __restrict__ qc, float* __restrict__ kc,
    float* __restrict__ qcT, float* __restrict__ dk) {
  __shared__ float sbuf[4];
  const int c = blockIdx.x, t = threadIdx.x;   // t indexes dim (DIM == TPB)
  const float denom = fmaxf((float)gcnt[c], EPSV);
  const float sq = gsq[c * DIM + t] / denom;
  const float sk = gsk[c * DIM + t] / denom;
  const float nq = blockReduceSum(sq * sq, sbuf);
  const float nk = blockReduceSum(sk * sk, sbuf);
  const float qv = sq / fmaxf(sqrtf(nq), EPSV);
  const float kv = sk / fmaxf(sqrtf(nk), EPSV);
  qc[c * DIM + t] = qv;
  kc[c * DIM + t] = kv;
  qcT[t * NCLU + c] = qv;
  const float dot = blockReduceSum(qv * kv, sbuf);
  if (t == 0) dk[c] = dot / TEMPERATURE;
}

// ---- K4: per-row similarity + masked logsumexp -> row loss ----
__global__ __launch_bounds__(TPB) void k_rowloss(
    const float* __restrict__ qc, const float* __restrict__ qcT,
    const float* __restrict__ dk, const int* __restrict__ gcnt,
    float* __restrict__ rowloss) {
  __shared__ float qrow[DIM];
  __shared__ float sbuf[4];
  const int c = blockIdx.x, t = threadIdx.x;
  qrow[t] = qc[c * DIM + t];
  __syncthreads();

  float v = -INFINITY;
  if (t < NCLU) {
    float dot = 0.f;
#pragma unroll 8
    for (int d = 0; d < DIM; ++d) dot += qrow[d] * qcT[d * NCLU + t];
    v = dot * (1.0f / TEMPERATURE);       // /0.5 == *2.0, exact
    if (t == c) v = dk[c];                // diag <- d_k (already /T)
    if (gcnt[t] == 0) v = -10.f;          // column mask AFTER diag set
  }
  const float m    = blockReduceMax(v, sbuf);
  const float e    = (t < NCLU) ? expf(v - m) : 0.f;
  const float ssum = blockReduceSum(e, sbuf);
  if (t == 0) {
    float loss = 0.f;
    if (gcnt[c] != 0) loss = -dk[c] + m + logf(ssum);
    rowloss[c] = loss;
  }
}

// ---- K5: final scalar ----
__global__ __launch_bounds__(TPB) void k_final(
    const float* __restrict__ rowloss, const int* __restrict__ gcnt,
    float* __restrict__ out) {
  __shared__ float sbuf[4];
  const int t = threadIdx.x;
  const float ls = (t < NCLU) ? rowloss[t] : 0.f;
  const float nz = (t < NCLU && gcnt[t] == 0) ? 1.f : 0.f;
  const float total = blockReduceSum(ls, sbuf);
  const float nzero = blockReduceSum(nz, sbuf);
  if (t == 0) out[0] = total / ((float)NCLU - nzero);
}

extern "C" void kernel_launch(void* const* d_in, const int* in_sizes, int n_in,
                              void* d_out, int out_size, void* d_ws, size_t ws_size,
                              hipStream_t stream) {
  const float* q  = (const float*)d_in[0];
  const float* k  = (const float*)d_in[1];
  const int* lab  = (const int*)d_in[2];
  const int n = in_sizes[0] / DIM;

  float* gsq      = (float*)d_ws;           // NCLU*DIM f32
  float* gsk      = gsq + NCLU * DIM;       // NCLU*DIM f32
  int*   ghist    = (int*)(gsk + NCLU * DIM);   // NCLU (end of zeroed region)
  int*   offsets  = ghist + NCLU;           // NCLU (written by k_scan)
  int*   gcursor  = offsets + NCLU;         // NCLU (written by k_scan)
  int*   order    = gcursor + NCLU;         // n
  float* qc       = (float*)(order + n);    // NCLU*DIM
  float* kc       = qc + NCLU * DIM;        // NCLU*DIM
  float* qcT      = kc + NCLU * DIM;        // DIM*NCLU
  float* dk       = qcT + DIM * NCLU;       // NCLU
  float* rowloss  = dk + NCLU;              // NCLU

  // Zero accumulators (gsq, gsk, ghist are contiguous).
  hipMemsetAsync(d_ws, 0,
                 (size_t)(2 * NCLU * DIM) * sizeof(float) + NCLU * sizeof(int),
                 stream);

  k_hist   <<<HBLK, TPB, 0, stream>>>(lab, n, ghist);
  k_scan   <<<1, 64, 0, stream>>>(ghist, offsets, gcursor);
  k_scatter<<<SBLK, TPB, 0, stream>>>(lab, n, gcursor, order);
  dim3 g2(NCLU, SPLIT);
  k_gather <<<g2, TPB, 0, stream>>>(q, k, order, offsets, ghist, gsq, gsk);
  k_centers<<<NCLU, TPB, 0, stream>>>(gsq, gsk, ghist, qc, kc, qcT, dk);
  k_rowloss<<<NCLU, TPB, 0, stream>>>(qc, qcT, dk, ghist, rowloss);
  k_final  <<<1, TPB, 0, stream>>>(rowloss, ghist, (float*)d_out);
}